// Round 1
// 273.512 us; speedup vs baseline: 1.0145x; 1.0145x over previous
//
#include <hip/hip_runtime.h>

// Problem constants (from reference)
#define Bc 2
#define Vc 5
#define Cc 32
#define Hc 256
#define Wc 320
#define Nc 40000
#define HWc (Hc * Wc)

typedef float v2f __attribute__((ext_vector_type(2)));

__device__ __forceinline__ unsigned bf16_rn(float x) {
    unsigned u = __float_as_uint(x);
    return (u + 0x7fffu + ((u >> 16) & 1u)) >> 16;   // round-to-nearest-even
}

// ---------------------------------------------------------------------------
// Pass 1: transpose + convert: fm (BV,C,HW) f32 -> fmT in HALF-IMAGE layout:
//   (bv*2 + half, HW, 16ch) bf16.  Half-pixel = 32 B, half-image = 2.62 MB
//   (< 4 MiB per-XCD L2 — the point of the split).
// Block: 64 hw x 32 c tile.
// ---------------------------------------------------------------------------
__global__ void __launch_bounds__(256)
transpose_bf16_kernel(const float* __restrict__ fm, unsigned short* __restrict__ fmT)
{
    __shared__ float tile[Cc][65];   // +1 pad: conflict-free both phases
    const int bv  = blockIdx.y;
    const int hw0 = blockIdx.x * 64;
    const int t   = threadIdx.x;

    const int tx = t & 63;
    const int ty = t >> 6;                  // 0..3
    const float* src = fm + (size_t)bv * Cc * HWc + hw0;
    #pragma unroll
    for (int i = 0; i < 8; ++i) {
        int c = ty * 8 + i;
        tile[c][tx] = __builtin_nontemporal_load(&src[(size_t)c * HWc + tx]);
    }
    __syncthreads();

    // Each thread packs one 16B chunk (8 channels) of one pixel.
    const int cq = t & 3;                   // chunk: channels cq*8 .. cq*8+7
    const int hw = t >> 2;                  // 0..63
    unsigned r[4];
    #pragma unroll
    for (int j = 0; j < 4; ++j) {
        float a = tile[cq * 8 + 2 * j][hw];
        float b = tile[cq * 8 + 2 * j + 1][hw];
        r[j] = bf16_rn(a) | (bf16_rn(b) << 16);
    }
    const int half = cq >> 1;               // which 16-channel half-image
    const int sub  = cq & 1;                // which 16B chunk within half-pixel
    uint4* dst = (uint4*)fmT
               + ((size_t)(bv * 2 + half) * HWc + (hw0 + hw)) * 2 + sub;
    *dst = make_uint4(r[0], r[1], r[2], r[3]);
}

// ---------------------------------------------------------------------------
// Pass 2: project + 5 bilinear samples. Virtual thread = (bvh, n, cq2);
// bvh = bv*2+half selects a 2.62 MB half-image, cq2 selects the 16B chunk
// (8 channels). Blocks are remapped so each XCD works a contiguous virtual
// range -> one half-image resident per XCD L2 at a time.
// ---------------------------------------------------------------------------
__device__ __forceinline__ void corner_setup(float ix, float iy, float coef,
                                             float wk[4], int pix[4])
{
    float x0f = floorf(ix), y0f = floorf(iy);
    float wx = ix - x0f, wy = iy - y0f;
    int x0 = (int)x0f, y0 = (int)y0f;
    float wg0 = (1.0f - wx) * (1.0f - wy);
    float wg1 = wx * (1.0f - wy);
    float wg2 = (1.0f - wx) * wy;
    float wg3 = wx * wy;
    float wg[4] = {wg0, wg1, wg2, wg3};
    #pragma unroll
    for (int k = 0; k < 4; ++k) {
        int xc = x0 + (k & 1);
        int yc = y0 + (k >> 1);
        bool valid = (xc >= 0) & (xc < Wc) & (yc >= 0) & (yc < Hc);
        wk[k] = valid ? coef * wg[k] : 0.0f;
        int xcl = min(max(xc, 0), Wc - 1);
        int ycl = min(max(yc, 0), Hc - 1);
        pix[k] = ycl * Wc + xcl;
    }
}

#define NBLK 6250            // total blocks = BV*2 * N * 2 / 256
#define XQ   781             // NBLK / 8
#define XR   2               // NBLK % 8

__global__ void __launch_bounds__(256)
fgf_main(const unsigned short* __restrict__ fmT,
         const float* __restrict__ pts,
         const float* __restrict__ Kmat,
         const float* __restrict__ Emat,
         float* __restrict__ out_feat,
         float* __restrict__ out_grad)
{
    // Bijective XCD-concentrating remap (m204 form): XCD x gets a contiguous
    // chunk of virtual block ids.
    const int b0  = blockIdx.x;
    const int xcd = b0 & 7;
    const int i   = b0 >> 3;
    const int vb  = (xcd < XR) ? xcd * (XQ + 1) + i
                               : XR * (XQ + 1) + (xcd - XR) * XQ + i;

    const int v    = vb * 256 + (int)threadIdx.x;   // < 1.6M
    const int cq2  = v & 1;                         // 16B chunk within half-pixel
    const int rest = v >> 1;                        // < 800000
    const int n    = rest % Nc;
    const int bvh  = rest / Nc;                     // 0..19: (bv, half)
    const int bv   = bvh >> 1;
    const int half = bvh & 1;
    const int b    = bv / Vc;

    // Point (B,3,N)
    const float* p = pts + (size_t)(b * 3) * Nc + n;
    float px = p[0];
    float py = p[Nc];
    float pz = p[2 * Nc];

    // Extrinsics (B,V,3,4), intrinsics (B,V,3,3)
    const float* Ep = Emat + bv * 12;
    const float* Kp = Kmat + bv * 9;
    float x = Ep[0] * px + Ep[1] * py + Ep[2]  * pz + Ep[3];
    float y = Ep[4] * px + Ep[5] * py + Ep[6]  * pz + Ep[7];
    float z = Ep[8] * px + Ep[9] * py + Ep[10] * pz + Ep[11];
    float xz = x / z;
    float yz = y / z;
    float u = Kp[0] * xz + Kp[1] * yz + Kp[2];
    float vv = Kp[3] * xz + Kp[4] * yz + Kp[5];

    const float sxp = (float)Wc / (float)(Wc - 1);   // pixel-space sample offset
    const float syp = (float)Hc / (float)(Hc - 1);
    float ix = (u  - 0.5f) * sxp - 0.5f;
    float iy = (vv - 0.5f) * syp - 0.5f;

    // Half-image base; gather offset = pix * 32 B (fits 32-bit easily)
    const uint4* base4 = (const uint4*)fmT + (size_t)bvh * (HWc * 2) + cq2;

    const float ox[5] = {0.0f, -sxp, sxp, 0.0f, 0.0f};
    const float oy[5] = {0.0f, 0.0f, 0.0f, -syp, syp};
    const float cf[5] = {1.0f, -0.5f, 0.5f, -0.5f, 0.5f};
    const int   as[5] = {0, 1, 1, 2, 2};   // accumulator select: feat, gx, gy

    float acc[3][8];
    #pragma unroll
    for (int a = 0; a < 3; ++a)
        #pragma unroll
        for (int j = 0; j < 8; ++j) acc[a][j] = 0.0f;

    float wk[2][4];
    int   pix[2][4];
    uint4 rg[2][4];

    // prologue: sample 0
    corner_setup(ix + ox[0], iy + oy[0], cf[0], wk[0], pix[0]);
    #pragma unroll
    for (int k = 0; k < 4; ++k) rg[0][k] = base4[(unsigned)pix[0][k] * 2u];

    #pragma unroll
    for (int s = 0; s < 5; ++s) {
        int cur = s & 1;
        if (s < 4) {
            int nxt = cur ^ 1;
            corner_setup(ix + ox[s + 1], iy + oy[s + 1], cf[s + 1], wk[nxt], pix[nxt]);
            #pragma unroll
            for (int k = 0; k < 4; ++k) rg[nxt][k] = base4[(unsigned)pix[nxt][k] * 2u];
        }
        float* a = acc[as[s]];
        #pragma unroll
        for (int k = 0; k < 4; ++k) {
            uint4 w = rg[cur][k];
            float ww = wk[cur][k];
            a[0] = fmaf(ww, __uint_as_float(w.x << 16),          a[0]);
            a[1] = fmaf(ww, __uint_as_float(w.x & 0xffff0000u), a[1]);
            a[2] = fmaf(ww, __uint_as_float(w.y << 16),          a[2]);
            a[3] = fmaf(ww, __uint_as_float(w.y & 0xffff0000u), a[3]);
            a[4] = fmaf(ww, __uint_as_float(w.z << 16),          a[4]);
            a[5] = fmaf(ww, __uint_as_float(w.z & 0xffff0000u), a[5]);
            a[6] = fmaf(ww, __uint_as_float(w.w << 16),          a[6]);
            a[7] = fmaf(ww, __uint_as_float(w.w & 0xffff0000u), a[7]);
        }
    }

    // Outputs: feat (BV,C,N) f32, grad (BV,C,N,2) f32 — nontemporal (never
    // re-read, and we must NOT evict the resident half-image from L2).
    const int cbase = half * 16 + cq2 * 8;
    size_t obase = (size_t)bv * Cc * Nc + n;
    v2f* gp = (v2f*)out_grad;
    #pragma unroll
    for (int j = 0; j < 8; ++j) {
        int c = cbase + j;
        __builtin_nontemporal_store(acc[0][j], &out_feat[obase + (size_t)c * Nc]);
        v2f g = {acc[1][j], acc[2][j]};
        __builtin_nontemporal_store(g, &gp[obase + (size_t)c * Nc]);
    }
}

// ---------------------------------------------------------------------------
// Fallback (round-1 style, NCHW direct) if ws is too small.
// ---------------------------------------------------------------------------
__device__ __forceinline__ float fetch_px(const float* __restrict__ fm, int x, int y) {
    if (x < 0 || x >= Wc || y < 0 || y >= Hc) return 0.0f;
    return fm[y * Wc + x];
}
__device__ __forceinline__ float bilin(const float* __restrict__ fm, float ix, float iy) {
    float x0f = floorf(ix), y0f = floorf(iy);
    float wx = ix - x0f, wy = iy - y0f;
    int x0 = (int)x0f, y0 = (int)y0f;
    float v00 = fetch_px(fm, x0, y0);
    float v10 = fetch_px(fm, x0 + 1, y0);
    float v01 = fetch_px(fm, x0, y0 + 1);
    float v11 = fetch_px(fm, x0 + 1, y0 + 1);
    return (v00 * (1.0f - wx) + v10 * wx) * (1.0f - wy)
         + (v01 * (1.0f - wx) + v11 * wx) * wy;
}
__global__ void __launch_bounds__(256)
fgf_fallback(const float* __restrict__ fm,
             const float* __restrict__ pts,
             const float* __restrict__ Kmat,
             const float* __restrict__ Emat,
             float* __restrict__ out_feat,
             float* __restrict__ out_grad)
{
    int idx = blockIdx.x * 256 + threadIdx.x;
    const int total = Bc * Vc * Cc * Nc;
    if (idx >= total) return;
    int n = idx % Nc;
    int tcb = idx / Nc;
    int c = tcb % Cc;
    int bv = tcb / Cc;
    int b = bv / Vc;
    const float* p = pts + (size_t)(b * 3) * Nc + n;
    float px = p[0], py = p[Nc], pz = p[2 * Nc];
    const float* Ep = Emat + bv * 12;
    const float* Kp = Kmat + bv * 9;
    float x = Ep[0] * px + Ep[1] * py + Ep[2] * pz + Ep[3];
    float y = Ep[4] * px + Ep[5] * py + Ep[6] * pz + Ep[7];
    float z = Ep[8] * px + Ep[9] * py + Ep[10] * pz + Ep[11];
    float xz = x / z, yz = y / z;
    float u = Kp[0] * xz + Kp[1] * yz + Kp[2];
    float v = Kp[3] * xz + Kp[4] * yz + Kp[5];
    const float sxp = (float)Wc / (float)(Wc - 1);
    const float syp = (float)Hc / (float)(Hc - 1);
    float ix = (u - 0.5f) * sxp - 0.5f;
    float iy = (v - 0.5f) * syp - 0.5f;
    const float* f = fm + (size_t)(bv * Cc + c) * HWc;
    float feat = bilin(f, ix, iy);
    float fl = bilin(f, ix - sxp, iy);
    float fr = bilin(f, ix + sxp, iy);
    float ft = bilin(f, ix, iy - syp);
    float fb = bilin(f, ix, iy + syp);
    size_t o = (size_t)(bv * Cc + c) * Nc + n;
    out_feat[o] = feat;
    ((float2*)out_grad)[o] = make_float2(0.5f * (fr - fl), 0.5f * (fb - ft));
}

extern "C" void kernel_launch(void* const* d_in, const int* in_sizes, int n_in,
                              void* d_out, int out_size, void* d_ws, size_t ws_size,
                              hipStream_t stream) {
    const float* fm  = (const float*)d_in[0];  // (B,V,C,H,W)
    const float* pts = (const float*)d_in[1];  // (B,3,N)
    const float* K   = (const float*)d_in[2];  // (B,V,3,3)
    const float* E   = (const float*)d_in[3];  // (B,V,3,4)

    float* out_feat = (float*)d_out;                               // (B,V,C,N)
    float* out_grad = (float*)d_out + (size_t)Bc * Vc * Cc * Nc;   // (B,V,C,N,2)

    const size_t fmT_bytes = (size_t)Bc * Vc * Cc * HWc * sizeof(unsigned short); // 52,428,800

    if (ws_size >= fmT_bytes) {
        unsigned short* fmT = (unsigned short*)d_ws;
        dim3 tgrid(HWc / 64, Bc * Vc);
        transpose_bf16_kernel<<<tgrid, 256, 0, stream>>>(fm, fmT);
        fgf_main<<<NBLK, 256, 0, stream>>>(fmT, pts, K, E, out_feat, out_grad);
    } else {
        const int total = Bc * Vc * Cc * Nc;
        fgf_fallback<<<(total + 255) / 256, 256, 0, stream>>>(fm, pts, K, E, out_feat, out_grad);
    }
}